// Round 1
// baseline (557.335 us; speedup 1.0000x reference)
//
#include <hip/hip_runtime.h>

// LIF recurrence + online eligibility-trace gradient, decomposed:
//   u[b,t]  = x[b,t,:] . w                       (pass 1, GEMV)
//   v_t = a*v + u_t - vth*z ; z_t = v>vth        (pass 2 fwd, per-batch scalar)
//   s_t = u_t - v_t*wsq   (== eps@w)
//   q_t = s_{t+1} + a*q_{t+1}; c_t = v_t + q_t   (pass 2 bwd)
//   g[b,n] = sum_t c_t x[b,t,n] - (sum v^2) w[n] (init + pass 3 accumulation)

#define ALPHA 0.995f
#define VTH   2.0f

constexpr int B = 32;
constexpr int T = 1024;
constexpr int N = 2048;

// ---- Pass 1: uT[t*B + b] = dot(x[b,t,:], w). One wave per row, 4 waves/block.
__global__ __launch_bounds__(256) void gemv_kernel(const float* __restrict__ x,
                                                   const float* __restrict__ w,
                                                   float* __restrict__ uT) {
    const int wave = threadIdx.x >> 6;
    const int lane = threadIdx.x & 63;
    const int row  = blockIdx.x * 4 + wave;           // row in [0, B*T)
    const float* xr = x + (size_t)row * N;
    float sum = 0.f;
#pragma unroll
    for (int k = 0; k < 8; ++k) {
        const int idx = k * 256 + lane * 4;
        const float4 xv = *reinterpret_cast<const float4*>(xr + idx);
        const float4 wv = *reinterpret_cast<const float4*>(w + idx);
        sum += xv.x * wv.x + xv.y * wv.y + xv.z * wv.z + xv.w * wv.w;
    }
#pragma unroll
    for (int off = 32; off; off >>= 1) sum += __shfl_down(sum, off);
    if (lane == 0) {
        const int b = row >> 10;     // row / T
        const int t = row & 1023;    // row % T
        uT[t * B + b] = sum;
    }
}

// ---- Pass 2: per-batch forward scan (v, z, s, sum v^2) then backward scan (c).
// buf holds uT on entry; overwritten with s_t (forward), then c_t (backward).
__global__ __launch_bounds__(64) void scan_kernel(const float* __restrict__ w,
                                                  float* __restrict__ buf,
                                                  float* __restrict__ vT,
                                                  float* __restrict__ V2,
                                                  float* __restrict__ out_v,
                                                  float* __restrict__ out_z) {
    const int tid = threadIdx.x;  // 64 threads, one wave
    // wsq = sum w^2, butterfly so every lane has it
    float wsq = 0.f;
    for (int i = 0; i < N / 64; ++i) {
        const float wv = w[tid * (N / 64) + i];
        wsq += wv * wv;
    }
#pragma unroll
    for (int off = 32; off; off >>= 1) wsq += __shfl_xor(wsq, off);

    if (tid >= B) return;
    const int b = tid;

    float v = 0.f, z = 0.f, v2 = 0.f;
    for (int t = 0; t < T; ++t) {
        const float ut = buf[t * B + b];
        v = ALPHA * v + ut - VTH * z;
        z = (v > VTH) ? 1.f : 0.f;
        out_v[b * T + t] = v;
        out_z[b * T + t] = z;
        vT[t * B + b]    = v;
        buf[t * B + b]   = ut - v * wsq;   // s_t
        v2 += v * v;
    }
    V2[b] = v2;

    float q = 0.f;                          // q_{T-1} = 0
    for (int t = T - 1; t >= 0; --t) {
        const float st = buf[t * B + b];    // s_t
        const float vt = vT[t * B + b];
        buf[t * B + b] = vt + q;            // c_t = v_t + q_t
        q = st + ALPHA * q;                 // q_{t-1} = s_t + a*q_t
    }
}

// ---- Init: g[b,n] = -V2[b] * w[n]  (also clears the 0xAA poison)
__global__ __launch_bounds__(256) void init_grad(const float* __restrict__ w,
                                                 const float* __restrict__ V2,
                                                 float* __restrict__ g) {
    const int i = blockIdx.x * 256 + threadIdx.x;  // [0, B*N)
    const int b = i >> 11;   // / N
    const int n = i & 2047;  // % N
    g[i] = -V2[b] * w[n];
}

// ---- Pass 3: g[b, n] += sum_t c_t * x[b, t, n], t-chunked, atomic accumulation.
// grid = (T/64, N/1024, B), block = 256 threads, float4 per thread.
__global__ __launch_bounds__(256) void accum_kernel(const float* __restrict__ x,
                                                    const float* __restrict__ cT,
                                                    float* __restrict__ g) {
    __shared__ float cs[64];
    const int b   = blockIdx.z;
    const int nc  = blockIdx.y;
    const int t0  = blockIdx.x * 64;
    const int tid = threadIdx.x;
    if (tid < 64) cs[tid] = cT[(t0 + tid) * B + b];
    __syncthreads();

    const int n = nc * 1024 + tid * 4;
    const float* xb = x + ((size_t)b * T + t0) * N + n;
    float4 acc = {0.f, 0.f, 0.f, 0.f};
#pragma unroll 4
    for (int tt = 0; tt < 64; ++tt) {
        const float4 xv = *reinterpret_cast<const float4*>(xb + (size_t)tt * N);
        const float c = cs[tt];
        acc.x += c * xv.x;
        acc.y += c * xv.y;
        acc.z += c * xv.z;
        acc.w += c * xv.w;
    }
    float* gp = g + b * N + n;
    atomicAdd(gp + 0, acc.x);
    atomicAdd(gp + 1, acc.y);
    atomicAdd(gp + 2, acc.z);
    atomicAdd(gp + 3, acc.w);
}

extern "C" void kernel_launch(void* const* d_in, const int* in_sizes, int n_in,
                              void* d_out, int out_size, void* d_ws, size_t ws_size,
                              hipStream_t stream) {
    const float* x = (const float*)d_in[0];   // [B, T, N]
    const float* w = (const float*)d_in[1];   // [N]

    float* out   = (float*)d_out;
    float* out_v = out;                 // [B, T]
    float* out_z = out + B * T;         // [B, T]
    float* out_g = out + 2 * B * T;     // [B, N]

    // workspace layout (floats): buf[B*T] (u -> s -> c), vT[B*T], V2[B]
    float* buf = (float*)d_ws;
    float* vT  = buf + B * T;
    float* V2  = vT + B * T;

    gemv_kernel<<<(B * T) / 4, 256, 0, stream>>>(x, w, buf);
    scan_kernel<<<1, 64, 0, stream>>>(w, buf, vT, V2, out_v, out_z);
    init_grad<<<(B * N) / 256, 256, 0, stream>>>(w, V2, out_g);
    accum_kernel<<<dim3(T / 64, N / 1024, B), 256, 0, stream>>>(x, buf, out_g);
}

// Round 2
// 472.160 us; speedup vs baseline: 1.1804x; 1.1804x over previous
//
#include <hip/hip_runtime.h>

// LIF recurrence + online eligibility-trace gradient, decomposed:
//   u[b,t]  = x[b,t,:] . w                       (pass 1, GEMV, 2 rows/wave)
//   v_t = a*v + u_t - vth*z ; z_t = v>vth        (pass 2 fwd, LDS-staged scan)
//   s_t = u_t - v_t*wsq   (== eps@w)
//   q_t = s_{t+1} + a*q_{t+1}; c_t = v_t + q_t   (pass 2 bwd, LDS-staged)
//   gpart[tc,b,n] = sum_{t in tc} c_t x[b,t,n]   (pass 3, no atomics)
//   g[b,n] = sum_tc gpart - (sum v^2) w[n]       (pass 4 reduce, fused init)

#define ALPHA 0.995f
#define VTH   2.0f

constexpr int B = 32;
constexpr int T = 1024;
constexpr int N = 2048;
constexpr int CT = 128;           // timesteps per scan chunk
constexpr int NCH = T / CT;       // 8 chunks
constexpr int TCH = 64;           // timesteps per accum chunk
constexpr int NTC = T / TCH;      // 16 accum chunks

// ---- Pass 1: uT[t*B + b] = dot(x[b,t,:], w). 2 rows per wave, 4 waves/block.
__global__ __launch_bounds__(256) void gemv_kernel(const float* __restrict__ x,
                                                   const float* __restrict__ w,
                                                   float* __restrict__ uT) {
    const int wave = threadIdx.x >> 6;
    const int lane = threadIdx.x & 63;
    const int row0 = blockIdx.x * 8 + wave * 2;       // rows in [0, B*T)
    const float* xr0 = x + (size_t)row0 * N;
    const float* xr1 = xr0 + N;
    float s0 = 0.f, s1 = 0.f;
#pragma unroll
    for (int k = 0; k < 8; ++k) {
        const int idx = k * 256 + lane * 4;
        const float4 wv = *reinterpret_cast<const float4*>(w + idx);
        const float4 a  = *reinterpret_cast<const float4*>(xr0 + idx);
        const float4 b  = *reinterpret_cast<const float4*>(xr1 + idx);
        s0 += a.x * wv.x + a.y * wv.y + a.z * wv.z + a.w * wv.w;
        s1 += b.x * wv.x + b.y * wv.y + b.z * wv.z + b.w * wv.w;
    }
#pragma unroll
    for (int off = 32; off; off >>= 1) {
        s0 += __shfl_down(s0, off);
        s1 += __shfl_down(s1, off);
    }
    if (lane == 0) {
        const int b0 = row0 >> 10;    // row / T
        const int t0 = row0 & 1023;   // row % T
        uT[t0 * B + b0]       = s0;
        uT[(t0 + 1) * B + b0] = s1;
    }
}

// ---- Pass 2: LDS-staged forward + backward scan. One block, 256 threads.
// ubuf: u in [t*B+b]; sbuf gets s; cbuf gets c. out_v/out_z written [b*T+t].
__global__ __launch_bounds__(256) void scan_kernel(const float* __restrict__ w,
                                                   const float* __restrict__ ubuf,
                                                   float* __restrict__ sbuf,
                                                   float* __restrict__ cbuf,
                                                   float* __restrict__ V2,
                                                   float* __restrict__ out_v,
                                                   float* __restrict__ out_z) {
    __shared__ float u_lds[CT * B];          // [tt*B + b]
    __shared__ float v_lds[B * (CT + 1)];    // [b*(CT+1) + tt], padded
    __shared__ float z_lds[B * (CT + 1)];
    __shared__ float red[4];

    const int tid  = threadIdx.x;
    const int wave = tid >> 6;
    const int lane = tid & 63;

    // wsq = sum w^2 (block reduce)
    float wacc = 0.f;
#pragma unroll
    for (int i = 0; i < 8; ++i) {
        const float wv = w[i * 256 + tid];
        wacc += wv * wv;
    }
#pragma unroll
    for (int off = 32; off; off >>= 1) wacc += __shfl_xor(wacc, off);
    if (lane == 0) red[wave] = wacc;
    __syncthreads();
    const float wsq = red[0] + red[1] + red[2] + red[3];

    float v = 0.f, z = 0.f, v2 = 0.f;

    // ---------------- forward ----------------
    for (int cc = 0; cc < NCH; ++cc) {
        const int t0 = cc * CT;
#pragma unroll
        for (int k = 0; k < 4; ++k) {
            const int idx = k * 1024 + tid * 4;
            *reinterpret_cast<float4*>(&u_lds[idx]) =
                *reinterpret_cast<const float4*>(&ubuf[t0 * B + idx]);
        }
        __syncthreads();
        if (tid < 32) {
            const int b = tid;
#pragma unroll 4
            for (int tt = 0; tt < CT; ++tt) {
                const float ut = u_lds[tt * B + b];
                v = ALPHA * v + ut - VTH * z;
                z = (v > VTH) ? 1.f : 0.f;
                v_lds[b * (CT + 1) + tt] = v;
                z_lds[b * (CT + 1) + tt] = z;
                u_lds[tt * B + b] = ut - v * wsq;   // s_t
                v2 += v * v;
            }
        }
        __syncthreads();
#pragma unroll
        for (int k = 0; k < 4; ++k) {
            const int idx = k * 1024 + tid * 4;
            *reinterpret_cast<float4*>(&sbuf[t0 * B + idx]) =
                *reinterpret_cast<const float4*>(&u_lds[idx]);
        }
#pragma unroll
        for (int k = 0; k < 16; ++k) {
            const int idx = k * 256 + tid;
            const int b  = idx >> 7;
            const int tt = idx & (CT - 1);
            out_v[b * T + t0 + tt] = v_lds[b * (CT + 1) + tt];
            out_z[b * T + t0 + tt] = z_lds[b * (CT + 1) + tt];
        }
        __syncthreads();
    }
    if (tid < 32) V2[tid] = v2;

    // ---------------- backward ----------------
    float q = 0.f;
    for (int cc = NCH - 1; cc >= 0; --cc) {
        const int t0 = cc * CT;
#pragma unroll
        for (int k = 0; k < 4; ++k) {
            const int idx = k * 1024 + tid * 4;
            *reinterpret_cast<float4*>(&u_lds[idx]) =
                *reinterpret_cast<const float4*>(&sbuf[t0 * B + idx]);
        }
#pragma unroll
        for (int k = 0; k < 16; ++k) {
            const int idx = k * 256 + tid;
            const int b  = idx >> 7;
            const int tt = idx & (CT - 1);
            v_lds[b * (CT + 1) + tt] = out_v[b * T + t0 + tt];
        }
        __syncthreads();
        if (tid < 32) {
            const int b = tid;
#pragma unroll 4
            for (int tt = CT - 1; tt >= 0; --tt) {
                const float st = u_lds[tt * B + b];
                const float vt = v_lds[b * (CT + 1) + tt];
                u_lds[tt * B + b] = vt + q;          // c_t = v_t + q_t
                q = st + ALPHA * q;                  // q_{t-1}
            }
        }
        __syncthreads();
#pragma unroll
        for (int k = 0; k < 4; ++k) {
            const int idx = k * 1024 + tid * 4;
            *reinterpret_cast<float4*>(&cbuf[t0 * B + idx]) =
                *reinterpret_cast<const float4*>(&u_lds[idx]);
        }
        __syncthreads();
    }
}

// ---- Pass 3: gpart[tc][b][n] = sum_{t in chunk tc} c_t * x[b,t,n]. No atomics.
// grid = (NTC, N/1024, B), block = 256 threads, float4 per thread.
__global__ __launch_bounds__(256) void accum_kernel(const float* __restrict__ x,
                                                    const float* __restrict__ cT,
                                                    float* __restrict__ gpart) {
    __shared__ float cs[TCH];
    const int b   = blockIdx.z;
    const int nc  = blockIdx.y;
    const int tc  = blockIdx.x;
    const int t0  = tc * TCH;
    const int tid = threadIdx.x;
    if (tid < TCH) cs[tid] = cT[(t0 + tid) * B + b];
    __syncthreads();

    const int n = nc * 1024 + tid * 4;
    const float* xb = x + ((size_t)b * T + t0) * N + n;
    float4 acc = {0.f, 0.f, 0.f, 0.f};
#pragma unroll 4
    for (int tt = 0; tt < TCH; ++tt) {
        const float4 xv = *reinterpret_cast<const float4*>(xb + (size_t)tt * N);
        const float c = cs[tt];
        acc.x += c * xv.x;
        acc.y += c * xv.y;
        acc.z += c * xv.z;
        acc.w += c * xv.w;
    }
    *reinterpret_cast<float4*>(gpart + ((size_t)tc * B + b) * N + n) = acc;
}

// ---- Pass 4: g[b,n] = sum_tc gpart[tc][b][n] - V2[b]*w[n]
__global__ __launch_bounds__(256) void reduce_kernel(const float* __restrict__ gpart,
                                                     const float* __restrict__ w,
                                                     const float* __restrict__ V2,
                                                     float* __restrict__ g) {
    const int i = blockIdx.x * 256 + threadIdx.x;   // [0, B*N)
    const int b = i >> 11;
    const int n = i & (N - 1);
    float acc = -V2[b] * w[n];
#pragma unroll
    for (int tc = 0; tc < NTC; ++tc) acc += gpart[tc * (B * N) + i];
    g[i] = acc;
}

extern "C" void kernel_launch(void* const* d_in, const int* in_sizes, int n_in,
                              void* d_out, int out_size, void* d_ws, size_t ws_size,
                              hipStream_t stream) {
    const float* x = (const float*)d_in[0];   // [B, T, N]
    const float* w = (const float*)d_in[1];   // [N]

    float* out   = (float*)d_out;
    float* out_v = out;                 // [B, T]
    float* out_z = out + B * T;         // [B, T]
    float* out_g = out + 2 * B * T;     // [B, N]

    // workspace (floats): ubuf[B*T], sbuf[B*T], cbuf[B*T], V2[B], gpart[NTC*B*N]
    float* ubuf  = (float*)d_ws;
    float* sbuf  = ubuf + B * T;
    float* cbuf  = sbuf + B * T;
    float* V2    = cbuf + B * T;
    float* gpart = V2 + B;

    gemv_kernel<<<(B * T) / 8, 256, 0, stream>>>(x, w, ubuf);
    scan_kernel<<<1, 256, 0, stream>>>(w, ubuf, sbuf, cbuf, V2, out_v, out_z);
    accum_kernel<<<dim3(NTC, N / 1024, B), 256, 0, stream>>>(x, cbuf, gpart);
    reduce_kernel<<<(B * N) / 256, 256, 0, stream>>>(gpart, w, V2, out_g);
}

// Round 4
// 461.949 us; speedup vs baseline: 1.2065x; 1.0221x over previous
//
#include <hip/hip_runtime.h>

// LIF recurrence + online eligibility-trace gradient, decomposed:
//   u[b,t]  = x[b,t,:] . w                       (pass 1, GEMV, 4 rows/wave, NT loads)
//   v_t = a*v + u_t - vth*z ; z_t = v>vth        (pass 2 fwd, LDS scan, CT=256)
//   s_t = u_t - v_t*wsq   (== eps@w)
//   q_t = s_{t+1} + a*q_{t+1}; c_t = v_t + q_t   (pass 2 bwd)
//   gpart[tc,b,n] = sum_{t in tc} c_t x[b,t,n]   (pass 3, NTC=8 partials)
//   g[b,n] = sum_tc gpart - (sum v^2) w[n]       (pass 4 reduce, fused init)

#define ALPHA 0.995f
#define VTH   2.0f

constexpr int B = 32;
constexpr int T = 1024;
constexpr int N = 2048;
constexpr int CT  = 256;          // timesteps per scan chunk (LDS: 2x32KB = 64KB)
constexpr int NCH = T / CT;       // 4 scan chunks
constexpr int TCH = 128;          // timesteps per accum chunk
constexpr int NTC = T / TCH;      // 8 accum partials

// native vector type — __builtin_nontemporal_load requires int/float/ptr vectors,
// not HIP_vector_type<float,4>
typedef float floatx4 __attribute__((ext_vector_type(4)));

__device__ inline floatx4 ntload4(const float* p) {
    return __builtin_nontemporal_load(reinterpret_cast<const floatx4*>(p));
}

// ---- Pass 1: uT[t*B + b] = dot(x[b,t,:], w). 4 rows per wave, 4 waves/block.
__global__ __launch_bounds__(256) void gemv_kernel(const float* __restrict__ x,
                                                   const float* __restrict__ w,
                                                   float* __restrict__ uT) {
    const int wave = threadIdx.x >> 6;
    const int lane = threadIdx.x & 63;
    const int row0 = blockIdx.x * 16 + wave * 4;      // rows in [0, B*T)
    const float* xr = x + (size_t)row0 * N;
    float s0 = 0.f, s1 = 0.f, s2 = 0.f, s3 = 0.f;
#pragma unroll
    for (int k = 0; k < 8; ++k) {
        const int idx = k * 256 + lane * 4;
        const floatx4 wv = *reinterpret_cast<const floatx4*>(w + idx);
        const floatx4 a = ntload4(xr + idx);
        const floatx4 b = ntload4(xr + N + idx);
        const floatx4 c = ntload4(xr + 2 * N + idx);
        const floatx4 d = ntload4(xr + 3 * N + idx);
        s0 += a.x * wv.x + a.y * wv.y + a.z * wv.z + a.w * wv.w;
        s1 += b.x * wv.x + b.y * wv.y + b.z * wv.z + b.w * wv.w;
        s2 += c.x * wv.x + c.y * wv.y + c.z * wv.z + c.w * wv.w;
        s3 += d.x * wv.x + d.y * wv.y + d.z * wv.z + d.w * wv.w;
    }
#pragma unroll
    for (int off = 32; off; off >>= 1) {
        s0 += __shfl_down(s0, off);
        s1 += __shfl_down(s1, off);
        s2 += __shfl_down(s2, off);
        s3 += __shfl_down(s3, off);
    }
    if (lane == 0) {
        const int b0 = row0 >> 10;    // row / T  (16-row groups never straddle batches)
        const int t0 = row0 & 1023;   // row % T
        uT[(t0 + 0) * B + b0] = s0;
        uT[(t0 + 1) * B + b0] = s1;
        uT[(t0 + 2) * B + b0] = s2;
        uT[(t0 + 3) * B + b0] = s3;
    }
}

// ---- Pass 2: LDS scan, one block, 256 threads. CT=256 chunks, 64KB LDS.
// u_lds holds u -> s (fwd, in place) and s -> c (bwd, in place), t-major [tt*32+b].
// v_st is swizzled [tt*32 + ((b+tt)&31)]: conflict-free for both the serial
// (lanes=b, fixed tt) and coalesced (consecutive tt, fixed b) access patterns.
__global__ __launch_bounds__(256) void scan_kernel(const float* __restrict__ w,
                                                   const float* __restrict__ ubuf,
                                                   float* __restrict__ sbuf,
                                                   float* __restrict__ cbuf,
                                                   float* __restrict__ V2,
                                                   float* __restrict__ out_v,
                                                   float* __restrict__ out_z) {
    __shared__ float u_lds[CT * B];   // 32 KB
    __shared__ float v_st[CT * B];    // 32 KB
    const int tid  = threadIdx.x;
    const int lane = tid & 63;

    // wsq = sum w^2 — each wave computes it redundantly (8KB, L1-hot), no LDS needed
    float wacc = 0.f;
#pragma unroll
    for (int i = 0; i < N / 64; ++i) {
        const float wv = w[i * 64 + lane];
        wacc += wv * wv;
    }
#pragma unroll
    for (int off = 32; off; off >>= 1) wacc += __shfl_xor(wacc, off);
    const float wsq = wacc;

    float v = 0.f, z = 0.f, v2 = 0.f;

    // ---------------- forward ----------------
    for (int cc = 0; cc < NCH; ++cc) {
        const int base = cc * CT * B;
        const int t0   = cc * CT;
#pragma unroll
        for (int k = 0; k < 8; ++k) {
            const int j = k * 1024 + tid * 4;
            *reinterpret_cast<floatx4*>(&u_lds[j]) =
                *reinterpret_cast<const floatx4*>(&ubuf[base + j]);
        }
        __syncthreads();
        if (tid < 32) {
            const int b = tid;
#pragma unroll 4
            for (int tt = 0; tt < CT; ++tt) {
                const float ut = u_lds[tt * 32 + b];
                v = ALPHA * v + ut - VTH * z;
                z = (v > VTH) ? 1.f : 0.f;
                u_lds[tt * 32 + b] = ut - v * wsq;        // s_t
                v_st[tt * 32 + ((b + tt) & 31)] = v;
                v2 += v * v;
            }
        }
        __syncthreads();
#pragma unroll
        for (int k = 0; k < 8; ++k) {
            const int j = k * 1024 + tid * 4;
            *reinterpret_cast<floatx4*>(&sbuf[base + j]) =
                *reinterpret_cast<const floatx4*>(&u_lds[j]);
        }
#pragma unroll
        for (int k = 0; k < 32; ++k) {
            const int idx = k * 256 + tid;
            const int b  = idx >> 8;
            const int tt = idx & 255;
            const float vv = v_st[tt * 32 + ((b + tt) & 31)];
            out_v[b * T + t0 + tt] = vv;
            out_z[b * T + t0 + tt] = (vv > VTH) ? 1.f : 0.f;
        }
        __syncthreads();
    }
    if (tid < 32) V2[tid] = v2;

    // ---------------- backward ----------------
    float q = 0.f;
    for (int cc = NCH - 1; cc >= 0; --cc) {
        const int base = cc * CT * B;
        const int t0   = cc * CT;
#pragma unroll
        for (int k = 0; k < 8; ++k) {
            const int j = k * 1024 + tid * 4;
            *reinterpret_cast<floatx4*>(&u_lds[j]) =
                *reinterpret_cast<const floatx4*>(&sbuf[base + j]);
        }
#pragma unroll
        for (int k = 0; k < 32; ++k) {
            const int idx = k * 256 + tid;
            const int b  = idx >> 8;
            const int tt = idx & 255;
            v_st[tt * 32 + ((b + tt) & 31)] = out_v[b * T + t0 + tt];
        }
        __syncthreads();
        if (tid < 32) {
            const int b = tid;
#pragma unroll 4
            for (int tt = CT - 1; tt >= 0; --tt) {
                const float st = u_lds[tt * 32 + b];
                const float vt = v_st[tt * 32 + ((b + tt) & 31)];
                u_lds[tt * 32 + b] = vt + q;              // c_t = v_t + q_t
                q = st + ALPHA * q;                       // q_{t-1}
            }
        }
        __syncthreads();
#pragma unroll
        for (int k = 0; k < 8; ++k) {
            const int j = k * 1024 + tid * 4;
            *reinterpret_cast<floatx4*>(&cbuf[base + j]) =
                *reinterpret_cast<const floatx4*>(&u_lds[j]);
        }
        __syncthreads();
    }
}

// ---- Pass 3: gpart[tc][b][n] = sum_{t in chunk tc} c_t * x[b,t,n].
// grid = (NTC, N/1024, B), block = 256 threads, float4 per thread.
__global__ __launch_bounds__(256) void accum_kernel(const float* __restrict__ x,
                                                    const float* __restrict__ cT,
                                                    float* __restrict__ gpart) {
    __shared__ float cs[TCH];
    const int b   = blockIdx.z;
    const int nc  = blockIdx.y;
    const int tc  = blockIdx.x;
    const int t0  = tc * TCH;
    const int tid = threadIdx.x;
    if (tid < TCH) cs[tid] = cT[(t0 + tid) * B + b];
    __syncthreads();

    const int n = nc * 1024 + tid * 4;
    const float* xb = x + ((size_t)b * T + t0) * N + n;
    floatx4 acc = {0.f, 0.f, 0.f, 0.f};
#pragma unroll 4
    for (int tt = 0; tt < TCH; ++tt) {
        const floatx4 xv = ntload4(xb + (size_t)tt * N);
        const float c = cs[tt];
        acc.x += c * xv.x;
        acc.y += c * xv.y;
        acc.z += c * xv.z;
        acc.w += c * xv.w;
    }
    *reinterpret_cast<floatx4*>(gpart + ((size_t)tc * B + b) * N + n) = acc;
}

// ---- Pass 4: g[b,n] = sum_tc gpart[tc][b][n] - V2[b]*w[n]
__global__ __launch_bounds__(256) void reduce_kernel(const float* __restrict__ gpart,
                                                     const float* __restrict__ w,
                                                     const float* __restrict__ V2,
                                                     float* __restrict__ g) {
    const int i = blockIdx.x * 256 + threadIdx.x;   // [0, B*N)
    const int b = i >> 11;
    const int n = i & (N - 1);
    float acc = -V2[b] * w[n];
#pragma unroll
    for (int tc = 0; tc < NTC; ++tc) acc += gpart[tc * (B * N) + i];
    g[i] = acc;
}

extern "C" void kernel_launch(void* const* d_in, const int* in_sizes, int n_in,
                              void* d_out, int out_size, void* d_ws, size_t ws_size,
                              hipStream_t stream) {
    const float* x = (const float*)d_in[0];   // [B, T, N]
    const float* w = (const float*)d_in[1];   // [N]

    float* out   = (float*)d_out;
    float* out_v = out;                 // [B, T]
    float* out_z = out + B * T;         // [B, T]
    float* out_g = out + 2 * B * T;     // [B, N]

    // workspace (floats): ubuf[B*T], sbuf[B*T], cbuf[B*T], V2[B], gpart[NTC*B*N]
    float* ubuf  = (float*)d_ws;
    float* sbuf  = ubuf + B * T;
    float* cbuf  = sbuf + B * T;
    float* V2    = cbuf + B * T;
    float* gpart = V2 + B;

    gemv_kernel<<<(B * T) / 16, 256, 0, stream>>>(x, w, ubuf);
    scan_kernel<<<1, 256, 0, stream>>>(w, ubuf, sbuf, cbuf, V2, out_v, out_z);
    accum_kernel<<<dim3(NTC, N / 1024, B), 256, 0, stream>>>(x, cbuf, gpart);
    reduce_kernel<<<(B * N) / 256, 256, 0, stream>>>(gpart, w, V2, out_g);
}

// Round 5
// 411.409 us; speedup vs baseline: 1.3547x; 1.1228x over previous
//
#include <hip/hip_runtime.h>

// LIF recurrence + online eligibility-trace gradient, decomposed:
//   u[b,t]  = x[b,t,:] . w                       (pass 1, GEMV, 4 rows/wave, NT loads)
//   v_t = a*v + u_t - vth*z ; z_t = v>vth        (pass 2: 32 blocks, one batch each)
//   s_t = u_t - v_t*wsq   (== eps@w)
//   q_t = s_{t+1} + a*q_{t+1}; c_t = v_t + q_t
//   gpart[tc,b,n] = sum_{t in tc} c_t x[b,t,n]   (pass 3, NTC=8 partials)
//   g[b,n] = sum_tc gpart - (sum v^2) w[n]       (pass 4 reduce, fused init)

#define ALPHA 0.995f
#define VTH   2.0f

constexpr int B = 32;
constexpr int T = 1024;
constexpr int N = 2048;
constexpr int TCH = 128;          // timesteps per accum chunk
constexpr int NTC = T / TCH;      // 8 accum partials

typedef float floatx4 __attribute__((ext_vector_type(4)));

__device__ inline floatx4 ntload4(const float* p) {
    return __builtin_nontemporal_load(reinterpret_cast<const floatx4*>(p));
}

// ---- Pass 1: u[b*T + t] = dot(x[b,t,:], w). 4 rows per wave, 4 waves/block.
__global__ __launch_bounds__(256) void gemv_kernel(const float* __restrict__ x,
                                                   const float* __restrict__ w,
                                                   float* __restrict__ u) {
    const int wave = threadIdx.x >> 6;
    const int lane = threadIdx.x & 63;
    const int row0 = blockIdx.x * 16 + wave * 4;      // rows in [0, B*T)
    const float* xr = x + (size_t)row0 * N;
    float s0 = 0.f, s1 = 0.f, s2 = 0.f, s3 = 0.f;
#pragma unroll
    for (int k = 0; k < 8; ++k) {
        const int idx = k * 256 + lane * 4;
        const floatx4 wv = *reinterpret_cast<const floatx4*>(w + idx);
        const floatx4 a = ntload4(xr + idx);
        const floatx4 b = ntload4(xr + N + idx);
        const floatx4 c = ntload4(xr + 2 * N + idx);
        const floatx4 d = ntload4(xr + 3 * N + idx);
        s0 += a.x * wv.x + a.y * wv.y + a.z * wv.z + a.w * wv.w;
        s1 += b.x * wv.x + b.y * wv.y + b.z * wv.z + b.w * wv.w;
        s2 += c.x * wv.x + c.y * wv.y + c.z * wv.z + c.w * wv.w;
        s3 += d.x * wv.x + d.y * wv.y + d.z * wv.z + d.w * wv.w;
    }
#pragma unroll
    for (int off = 32; off; off >>= 1) {
        s0 += __shfl_down(s0, off);
        s1 += __shfl_down(s1, off);
        s2 += __shfl_down(s2, off);
        s3 += __shfl_down(s3, off);
    }
    if (lane == 0) {
        floatx4 r = {s0, s1, s2, s3};
        *reinterpret_cast<floatx4*>(u + row0) = r;   // natural [B][T] layout
    }
}

// ---- Pass 2: one block per batch (32 blocks x 64 threads), all data in LDS.
// Per-block global traffic: read u[b,:] 4KB, write out_v/out_z/c 4KB each.
// Lane 0 does the serial fwd+bwd scans; chunked float4 LDS loads pipeline the
// ~120-cycle ds_read latency. Separate s/c buffers avoid aliasing stalls.
__global__ __launch_bounds__(64) void scan_kernel(const float* __restrict__ w,
                                                  const float* __restrict__ u,     // [B][T]
                                                  float* __restrict__ cbuf,        // [B][T]
                                                  float* __restrict__ V2,
                                                  float* __restrict__ out_v,
                                                  float* __restrict__ out_z) {
    __shared__ float u_lds[T];
    __shared__ float v_lds[T];
    __shared__ float s_lds[T];
    __shared__ float c_lds[T];
    const int b    = blockIdx.x;
    const int lane = threadIdx.x;

    // wsq = sum w^2 (wave butterfly; w is 8KB, L1-hot)
    float wacc = 0.f;
#pragma unroll
    for (int i = 0; i < N / 64; ++i) {
        const float wv = w[i * 64 + lane];
        wacc += wv * wv;
    }
#pragma unroll
    for (int off = 32; off; off >>= 1) wacc += __shfl_xor(wacc, off);
    const float wsq = wacc;

    // stage u[b,:] -> LDS (4 x 1KB coalesced float4 loads)
#pragma unroll
    for (int k = 0; k < T / 256; ++k) {
        const int j = (k * 64 + lane) * 4;
        *reinterpret_cast<floatx4*>(&u_lds[j]) =
            *reinterpret_cast<const floatx4*>(&u[b * T + j]);
    }
    __syncthreads();

    if (lane == 0) {
        float v = 0.f, z = 0.f, v2 = 0.f;
        // ---- forward: chunks of 32 so ds_reads pipeline ahead of the chain
        for (int cc = 0; cc < T / 32; ++cc) {
            const int base = cc * 32;
            floatx4 ub[8];
#pragma unroll
            for (int k = 0; k < 8; ++k)
                ub[k] = *reinterpret_cast<floatx4*>(&u_lds[base + k * 4]);
            floatx4 vb[8], sb[8];
#pragma unroll
            for (int k = 0; k < 8; ++k) {
#pragma unroll
                for (int e = 0; e < 4; ++e) {
                    const float ut = ub[k][e];
                    v = ALPHA * v + ut - VTH * z;
                    z = (v > VTH) ? 1.f : 0.f;
                    vb[k][e] = v;
                    sb[k][e] = ut - v * wsq;
                    v2 += v * v;
                }
            }
#pragma unroll
            for (int k = 0; k < 8; ++k) {
                *reinterpret_cast<floatx4*>(&v_lds[base + k * 4]) = vb[k];
                *reinterpret_cast<floatx4*>(&s_lds[base + k * 4]) = sb[k];
            }
        }
        V2[b] = v2;
        // ---- backward: q_{t-1} = s_t + a*q_t ; c_t = v_t + q_t
        float q = 0.f;
        for (int cc = T / 32 - 1; cc >= 0; --cc) {
            const int base = cc * 32;
            floatx4 sb[8], vb[8], cb[8];
#pragma unroll
            for (int k = 0; k < 8; ++k) {
                sb[k] = *reinterpret_cast<floatx4*>(&s_lds[base + k * 4]);
                vb[k] = *reinterpret_cast<floatx4*>(&v_lds[base + k * 4]);
            }
#pragma unroll
            for (int k = 7; k >= 0; --k) {
#pragma unroll
                for (int e = 3; e >= 0; --e) {
                    cb[k][e] = vb[k][e] + q;
                    q = sb[k][e] + ALPHA * q;
                }
            }
#pragma unroll
            for (int k = 0; k < 8; ++k)
                *reinterpret_cast<floatx4*>(&c_lds[base + k * 4]) = cb[k];
        }
    }
    __syncthreads();

    // writeout: coalesced float4 per array
#pragma unroll
    for (int k = 0; k < T / 256; ++k) {
        const int j = (k * 64 + lane) * 4;
        const floatx4 vv = *reinterpret_cast<floatx4*>(&v_lds[j]);
        floatx4 zz;
        zz.x = (vv.x > VTH) ? 1.f : 0.f;
        zz.y = (vv.y > VTH) ? 1.f : 0.f;
        zz.z = (vv.z > VTH) ? 1.f : 0.f;
        zz.w = (vv.w > VTH) ? 1.f : 0.f;
        *reinterpret_cast<floatx4*>(&out_v[b * T + j]) = vv;
        *reinterpret_cast<floatx4*>(&out_z[b * T + j]) = zz;
        *reinterpret_cast<floatx4*>(&cbuf[b * T + j]) =
            *reinterpret_cast<floatx4*>(&c_lds[j]);
    }
}

// ---- Pass 3: gpart[tc][b][n] = sum_{t in chunk tc} c_t * x[b,t,n].
// grid = (NTC, N/1024, B), block = 256 threads, float4 per thread.
__global__ __launch_bounds__(256) void accum_kernel(const float* __restrict__ x,
                                                    const float* __restrict__ c,   // [B][T]
                                                    float* __restrict__ gpart) {
    __shared__ float cs[TCH];
    const int b   = blockIdx.z;
    const int nc  = blockIdx.y;
    const int tc  = blockIdx.x;
    const int t0  = tc * TCH;
    const int tid = threadIdx.x;
    if (tid < TCH) cs[tid] = c[b * T + t0 + tid];
    __syncthreads();

    const int n = nc * 1024 + tid * 4;
    const float* xb = x + ((size_t)b * T + t0) * N + n;
    floatx4 acc = {0.f, 0.f, 0.f, 0.f};
#pragma unroll 8
    for (int tt = 0; tt < TCH; ++tt) {
        const floatx4 xv = ntload4(xb + (size_t)tt * N);
        const float cc = cs[tt];
        acc.x += cc * xv.x;
        acc.y += cc * xv.y;
        acc.z += cc * xv.z;
        acc.w += cc * xv.w;
    }
    *reinterpret_cast<floatx4*>(gpart + ((size_t)tc * B + b) * N + n) = acc;
}

// ---- Pass 4: g[b,n] = sum_tc gpart[tc][b][n] - V2[b]*w[n]
__global__ __launch_bounds__(256) void reduce_kernel(const float* __restrict__ gpart,
                                                     const float* __restrict__ w,
                                                     const float* __restrict__ V2,
                                                     float* __restrict__ g) {
    const int i = blockIdx.x * 256 + threadIdx.x;   // [0, B*N)
    const int b = i >> 11;
    const int n = i & (N - 1);
    float acc = -V2[b] * w[n];
#pragma unroll
    for (int tc = 0; tc < NTC; ++tc) acc += gpart[tc * (B * N) + i];
    g[i] = acc;
}

extern "C" void kernel_launch(void* const* d_in, const int* in_sizes, int n_in,
                              void* d_out, int out_size, void* d_ws, size_t ws_size,
                              hipStream_t stream) {
    const float* x = (const float*)d_in[0];   // [B, T, N]
    const float* w = (const float*)d_in[1];   // [N]

    float* out   = (float*)d_out;
    float* out_v = out;                 // [B, T]
    float* out_z = out + B * T;         // [B, T]
    float* out_g = out + 2 * B * T;     // [B, N]

    // workspace (floats): u[B*T], c[B*T], V2[B], gpart[NTC*B*N]
    float* u     = (float*)d_ws;
    float* c     = u + B * T;
    float* V2    = c + B * T;
    float* gpart = V2 + B;

    gemv_kernel<<<(B * T) / 16, 256, 0, stream>>>(x, w, u);
    scan_kernel<<<B, 64, 0, stream>>>(w, u, c, V2, out_v, out_z);
    accum_kernel<<<dim3(NTC, N / 1024, B), 256, 0, stream>>>(x, c, gpart);
    reduce_kernel<<<(B * N) / 256, 256, 0, stream>>>(gpart, w, V2, out_g);
}